// Round 19
// baseline (91.682 us; speedup 1.0000x reference)
//
#include <hip/hip_runtime.h>
#include <hip/hip_bf16.h>
#include <stdint.h>

// ====== DIAGNOSTIC: PAIR_REP=3 so pair lands in rocprof top-5 with counters.
// ====== proj also changed: A path global->reg (ldsA removed). Revert REP next.
#define PAIR_REP 3

// Problem constants
#define BB 64      // batch
#define LL 256     // x seq len
#define TT 64      // y seq len
#define DD 512     // input dim
#define EE 200     // embed dim
#define EP 208     // embed dim padded to 13*16
#define NKK 13     // K-steps in pair kernel (EP/16)
#define NROWS_X 16384   // 64*256
// Fragment-chunk layout: 1 chunk = 32 rows x 16 e = 64 lanes x 16 B = 1024 B.
// lane l holds row (l&31), e_local (l>>5)*8 .. +8, at shorts chunk*512 + l*8.
// Unified pT: chunk index = (global_row >> 5)*13 + n (x rows first, then y).
#define BSTRIDE 264                // proj bounce row stride in shorts
#define PBM 80                     // proj rows per block: 20480/80 = 256 = exact grid

typedef __attribute__((ext_vector_type(8))) short short8;
typedef __attribute__((ext_vector_type(4))) float floatx4;
typedef __attribute__((ext_vector_type(16))) float floatx16;

__device__ __forceinline__ short f2bf(float f) {
  uint32_t u = __builtin_bit_cast(uint32_t, f);
  u = (u + 0x7fffu + ((u >> 16) & 1u)) >> 16;  // RNE
  return (short)u;
}

__device__ __forceinline__ uint32_t pack2(float lo, float hi) {
  return __builtin_amdgcn_perm(__builtin_bit_cast(uint32_t, hi),
                               __builtin_bit_cast(uint32_t, lo), 0x07060302u);
}

typedef const __attribute__((address_space(1))) uint32_t gu32_t;
typedef __attribute__((address_space(3))) uint32_t lu32_t;
__device__ __forceinline__ void glds16(const void* g, void* l) {
  __builtin_amdgcn_global_load_lds((gu32_t*)g, (lu32_t*)l, 16, 0, 0);
}

// counted-vmcnt barrier (FIFO retire; counts BOTH glds and plain loads).
#define VMCNT_BARRIER(N) asm volatile("s_waitcnt vmcnt(" #N ") lgkmcnt(0)\n\ts_barrier" ::: "memory")

// ---------------- Kernel 0: W (200x512 f32) -> Wb (208x512 bf16, zero-padded), RNE
__global__ void wcvt_kernel(const float* __restrict__ W, short* __restrict__ Wb) {
  const int t = blockIdx.x * 256 + threadIdx.x;   // 0 .. 13311
  const int base = t * 8;
  const int e = base >> 9;
  short8 o;
  if (e < EE) {
    const floatx4 f0 = *(const floatx4*)(W + base);
    const floatx4 f1 = *(const floatx4*)(W + base + 4);
    o[0] = f2bf(f0.x); o[1] = f2bf(f0.y); o[2] = f2bf(f0.z); o[3] = f2bf(f0.w);
    o[4] = f2bf(f1.x); o[5] = f2bf(f1.y); o[6] = f2bf(f1.z); o[7] = f2bf(f1.w);
  } else {
    o = (short8)0;
  }
  *(short8*)(Wb + base) = o;
}

// ---------------- Kernel 1: projection GEMM -> fragment-layout pT
// A path now GLOBAL->REG (per-lane 32B contiguous, one-step prefetch) — ldsA
// removed: glds issue/step falls 1472 -> 832 chunks (−43%), A-swizzle VALU gone.
// B: triple-buffered glds, 832 chunks via tid<832 (13 waves, wave-uniform).
// VMCNT_BARRIER(3): steady-state outstanding/wave = [B(s+1), A(s)x2] = 3;
// prologue [B0,B1,A0x2]=4 -> retires B0. A-consumption in compute auto-retires
// older B entries (FIFO), so B(s) is always landed by barrier s.
__global__ __launch_bounds__(960, 1) void proj_kernel(const float* __restrict__ x,
                                                      const float* __restrict__ y,
                                                      const short* __restrict__ Wb,
                                                      const float* __restrict__ bias,
                                                      short* __restrict__ pT) {
  __shared__ __align__(16) char smem[43008];
  short* ldsB = (short*)smem;               // [3][208*32] bf16 = 39,936 B
  short* bounce = (short*)smem;             // [80][BSTRIDE] 42,240 B (after loop)

  const int tid  = threadIdx.x;
  const int lane = tid & 63;
  const int wid  = tid >> 6;          // 0..14
  const int r16   = lane & 15;
  const int khalf = lane >> 4;        // 0..3
  const int mw = wid % 5;             // M-tile (16 rows)
  const int eh = wid / 5;             // E-third
  const int nbase = (eh == 0) ? 0 : (eh == 1) ? 5 : 9;
  const int ncnt  = (eh == 0) ? 5 : 4;

  const int row0 = blockIdx.x * PBM;

  // This thread's A row (may straddle x/y boundary; per-lane select is fine
  // for plain loads).
  const int gr = row0 + mw * 16 + r16;
  const float* arow = (gr < NROWS_X) ? (x + (size_t)gr * DD)
                                     : (y + (size_t)(gr - NROWS_X) * DD);
  const float* abase = arow + khalf * 8;

  floatx4 acc[5];
#pragma unroll
  for (int n = 0; n < 5; n++) acc[n] = (floatx4){0.f, 0.f, 0.f, 0.f};

  // B chunk q (0..831): ldsB[r=q>>2][c=q&3] <- Wb[r][ks*32 + (c^((r>>1)&3))*8]
  auto stage = [&](int buf, int ks) {
    if (tid < 832) {                   // 13 waves exactly: wave-uniform
      const int q = tid;
      const int r = q >> 2, c = q & 3;
      glds16(Wb + (size_t)r * DD + ks * 32 + ((c ^ ((r >> 1) & 3)) << 3),
             &ldsB[buf * 6656 + q * 8]);
    }
  };

  floatx4 aCur0, aCur1, aNext0, aNext1;

  stage(0, 0);                        // issue order: B first (FIFO proof above)
  stage(1, 1);
  aCur0 = *(const floatx4*)(abase + 0);
  aCur1 = *(const floatx4*)(abase + 4);

  auto compute = [&](int s) {
    const int buf = s % 3;
    union { short8 s8; uint32_t u[4]; } af;
    af.u[0] = pack2(aCur0.x, aCur0.y);
    af.u[1] = pack2(aCur0.z, aCur0.w);
    af.u[2] = pack2(aCur1.x, aCur1.y);
    af.u[3] = pack2(aCur1.z, aCur1.w);
    const int bcol = (khalf ^ ((r16 >> 1) & 3)) << 3;
#pragma unroll
    for (int n = 0; n < 5; n++) {
      if (n < ncnt) {
        const int erow = (nbase + n) * 16 + r16;
        const short8 bfrag = *(const short8*)&ldsB[buf * 6656 + erow * 32 + bcol];
        acc[n] = __builtin_amdgcn_mfma_f32_16x16x32_bf16(af.s8, bfrag, acc[n], 0, 0, 0);
      }
    }
  };

  for (int s = 0; s < 15; s++) {
    VMCNT_BARRIER(3);                 // B(s) landed on every wave
    if (s + 2 < 16) stage((s + 2) % 3, s + 2);
    // prefetch A(s+1)
    aNext0 = *(const floatx4*)(abase + (s + 1) * 32);
    aNext1 = *(const floatx4*)(abase + (s + 1) * 32 + 4);
    compute(s);
    aCur0 = aNext0; aCur1 = aNext1;
  }
  VMCNT_BARRIER(0);
  compute(15);

  __syncthreads();   // all LDS reads done; reuse smem as bounce

  for (int n = 0; n < ncnt; n++) {
    const int e = (nbase + n) * 16 + r16;
    const float bv = (e < EE) ? bias[e] : 0.0f;
#pragma unroll
    for (int rr = 0; rr < 4; rr++) {
      const int lr = mw * 16 + khalf * 4 + rr;
      bounce[lr * BSTRIDE + e] = f2bf(acc[n][rr] + bv);
    }
  }
  __syncthreads();

  for (int c = tid; c < 2080; c += 960) {
    const int n    = c / 160;
    const int rem  = c - n * 160;
    const int lrow = rem >> 1;
    const int ehh  = rem & 1;
    const int g2   = row0 + lrow;
    const short8 piece = *(const short8*)&bounce[lrow * BSTRIDE + n * 16 + ehh * 8];
    *(short8*)&pT[((size_t)((g2 >> 5) * 13 + n)) * 512 + (size_t)(((ehh << 5) | (g2 & 31)) * 8)] = piece;
  }
}

// ---------------- Kernel 2: pair kernel — R18 structure, REP'd for profiling
__global__ __launch_bounds__(512, 1) void pair_kernel(const short* __restrict__ xpT,
                                                      const short* __restrict__ ypT,
                                                      float* __restrict__ S) {
  __shared__ __align__(16) char lds[2 * 53248 + 16384];
  float* red = (float*)(lds + 2 * 53248);   // [il 2][j 8][wj 4][64 t] = 16 KB

  const int tid  = threadIdx.x;
  const int lane = tid & 63;
  const int wid  = tid >> 6;       // 0..7
  const int il   = wid >> 2;       // i within pair
  const int wj   = wid & 3;        // lt-pair
  const int bid  = blockIdx.x;
  const int ip   = bid & 31;
  const int jo   = bid >> 5;       // 0..7
  const int i    = ip * 2 + il;
  const int j0   = jo * 8;

  auto stageB = [&](int g) {
    const short* src = ypT + (size_t)(j0 + g * 2) * 26 * 512;
    char* dst = lds + (g & 1) * 53248;
    for (int c = tid; c < 3328; c += 512)
      glds16(src + (size_t)c * 8, dst + c * 16);
  };

  for (int rep = 0; rep < PAIR_REP; rep++) {
    // A global->reg: 2 L-tiles x 13 kk fragments (104 VGPR)
    short8 a0[NKK], a1[NKK];
    {
      const short* ab0 = xpT + ((size_t)((i * 8 + wj * 2 + 0) * NKK)) * 512 + lane * 8;
      const short* ab1 = xpT + ((size_t)((i * 8 + wj * 2 + 1) * NKK)) * 512 + lane * 8;
#pragma unroll
      for (int kk = 0; kk < NKK; kk++) {
        a0[kk] = *(const short8*)(ab0 + kk * 512);
        a1[kk] = *(const short8*)(ab1 + kk * 512);
      }
    }

    stageB(0);
    __syncthreads();

    for (int g = 0; g < 4; g++) {
      if (g + 1 < 4) stageB(g + 1);

#pragma unroll
      for (int jj2 = 0; jj2 < 2; jj2++) {
        const int j = g * 2 + jj2;     // 0..7 within block
        const short* bbase = (const short*)(lds + (g & 1) * 53248) +
                             (size_t)(jj2 * 26 * 512) + lane * 8;

        floatx16 acc00, acc01, acc10, acc11;   // [m][nt]
#pragma unroll
        for (int r = 0; r < 16; r++) {
          acc00[r] = 0.f; acc01[r] = 0.f; acc10[r] = 0.f; acc11[r] = 0.f;
        }

#pragma unroll
        for (int kk = 0; kk < NKK; kk++) {
          const short8 b0 = *(const short8*)(bbase + (0 * NKK + kk) * 512);
          const short8 b1 = *(const short8*)(bbase + (1 * NKK + kk) * 512);
          acc00 = __builtin_amdgcn_mfma_f32_32x32x16_bf16(a0[kk], b0, acc00, 0, 0, 0);
          acc10 = __builtin_amdgcn_mfma_f32_32x32x16_bf16(a1[kk], b0, acc10, 0, 0, 0);
          acc01 = __builtin_amdgcn_mfma_f32_32x32x16_bf16(a0[kk], b1, acc01, 0, 0, 0);
          acc11 = __builtin_amdgcn_mfma_f32_32x32x16_bf16(a1[kk], b1, acc11, 0, 0, 0);
        }

        float v0 = acc00[0], v1 = acc01[0];
#pragma unroll
        for (int r = 0; r < 16; r++) {
          v0 = fmaxf(v0, acc00[r]); v0 = fmaxf(v0, acc10[r]);
          v1 = fmaxf(v1, acc01[r]); v1 = fmaxf(v1, acc11[r]);
        }
        v0 = fmaxf(v0, __shfl_xor(v0, 32, 64));
        v1 = fmaxf(v1, __shfl_xor(v1, 32, 64));
        if (lane < 32) {
          red[(((il * 8 + j) * 4 + wj)) * 64 + 0 * 32 + lane] = v0;
          red[(((il * 8 + j) * 4 + wj)) * 64 + 1 * 32 + lane] = v1;
        }
      }
      __syncthreads();   // buf (g+1)&1 staged; red for group g visible
    }

    // Final: 16 (il2,j) combos x 64 t; wave wid takes combos wid*2, wid*2+1.
#pragma unroll
    for (int rr2 = 0; rr2 < 2; rr2++) {
      const int combo = wid * 2 + rr2;   // 0..15
      const int il2 = combo >> 3;
      const int j   = combo & 7;
      const int t   = lane;
      float v = red[((il2 * 8 + j) * 4 + 0) * 64 + t];
      v = fmaxf(v, red[((il2 * 8 + j) * 4 + 1) * 64 + t]);
      v = fmaxf(v, red[((il2 * 8 + j) * 4 + 2) * 64 + t]);
      v = fmaxf(v, red[((il2 * 8 + j) * 4 + 3) * 64 + t]);
      v += __shfl_xor(v, 1, 64);
      v += __shfl_xor(v, 2, 64);
      v += __shfl_xor(v, 4, 64);
      v += __shfl_xor(v, 8, 64);
      v += __shfl_xor(v, 16, 64);
      v += __shfl_xor(v, 32, 64);
      if (t == 0) S[(ip * 2 + il2) * BB + j0 + j] = v * (1.0f / 64.0f);
    }
    __syncthreads();   // red reads done before next rep overwrites
  }
}

extern "C" void kernel_launch(void* const* d_in, const int* in_sizes, int n_in,
                              void* d_out, int out_size, void* d_ws, size_t ws_size,
                              hipStream_t stream) {
  const float* x = (const float*)d_in[0];   // 64*256*512
  const float* y = (const float*)d_in[1];   // 64*64*512
  const float* W = (const float*)d_in[2];   // 200*512
  const float* b = (const float*)d_in[3];   // 200
  float* S = (float*)d_out;                 // 64*64

  char* ws = (char*)d_ws;
  short* Wb = (short*)ws;                   // 208*512*2 = 212,992 B
  short* pT = (short*)(ws + 262144);        // 8320 chunks * 1024 B = 8,519,680 B
  short* ypT = pT + (size_t)6656 * 512;     // y starts at chunk 6656

  wcvt_kernel<<<52, 256, 0, stream>>>(W, Wb);
  proj_kernel<<<256, 960, 0, stream>>>(x, y, Wb, b, pT);
  pair_kernel<<<256, 512, 0, stream>>>(pT, ypT, S);
}

// Round 20
// 84.604 us; speedup vs baseline: 1.0837x; 1.0837x over previous
//
#include <hip/hip_runtime.h>
#include <hip/hip_bf16.h>
#include <stdint.h>

// Problem constants
#define BB 64      // batch
#define LL 256     // x seq len
#define TT 64      // y seq len
#define DD 512     // input dim
#define EE 200     // embed dim
#define EP 208     // embed dim padded to 13*16
#define NKK 13     // K-steps in pair kernel (EP/16)
#define NROWS_X 16384   // 64*256
// Fragment-chunk layout: 1 chunk = 32 rows x 16 e = 64 lanes x 16 B = 1024 B.
// lane l holds row (l&31), e_local (l>>5)*8 .. +8, at shorts chunk*512 + l*8.
// Unified pT: chunk index = (global_row >> 5)*13 + n (x rows first, then y).
#define BSTRIDE 264                // proj bounce row stride in shorts
#define PBM 80                     // proj rows per block: 20480/80 = 256 = exact grid

typedef __attribute__((ext_vector_type(8))) short short8;
typedef __attribute__((ext_vector_type(4))) float floatx4;
typedef __attribute__((ext_vector_type(16))) float floatx16;

__device__ __forceinline__ short f2bf(float f) {
  uint32_t u = __builtin_bit_cast(uint32_t, f);
  u = (u + 0x7fffu + ((u >> 16) & 1u)) >> 16;  // RNE
  return (short)u;
}

__device__ __forceinline__ uint32_t pack2(float lo, float hi) {
  return __builtin_amdgcn_perm(__builtin_bit_cast(uint32_t, hi),
                               __builtin_bit_cast(uint32_t, lo), 0x07060302u);
}

typedef const __attribute__((address_space(1))) uint32_t gu32_t;
typedef __attribute__((address_space(3))) uint32_t lu32_t;
__device__ __forceinline__ void glds16(const void* g, void* l) {
  __builtin_amdgcn_global_load_lds((gu32_t*)g, (lu32_t*)l, 16, 0, 0);
}

// counted-vmcnt barrier (FIFO retire; counts BOTH glds and plain loads).
#define VMCNT_BARRIER(N) asm volatile("s_waitcnt vmcnt(" #N ") lgkmcnt(0)\n\ts_barrier" ::: "memory")

// ---------------- Kernel 0: W (200x512 f32) -> Wb (208x512 bf16, zero-padded), RNE
__global__ void wcvt_kernel(const float* __restrict__ W, short* __restrict__ Wb) {
  const int t = blockIdx.x * 256 + threadIdx.x;   // 0 .. 13311
  const int base = t * 8;
  const int e = base >> 9;
  short8 o;
  if (e < EE) {
    const floatx4 f0 = *(const floatx4*)(W + base);
    const floatx4 f1 = *(const floatx4*)(W + base + 4);
    o[0] = f2bf(f0.x); o[1] = f2bf(f0.y); o[2] = f2bf(f0.z); o[3] = f2bf(f0.w);
    o[4] = f2bf(f1.x); o[5] = f2bf(f1.y); o[6] = f2bf(f1.z); o[7] = f2bf(f1.w);
  } else {
    o = (short8)0;
  }
  *(short8*)(Wb + base) = o;
}

// ---------------- Kernel 1: projection GEMM -> fragment-layout pT (R19 version)
// A path GLOBAL->REG with one-step prefetch; B triple-buffered glds (832
// chunks, 13 waves wave-uniform), VMCNT_BARRIER(3).
__global__ __launch_bounds__(960, 1) void proj_kernel(const float* __restrict__ x,
                                                      const float* __restrict__ y,
                                                      const short* __restrict__ Wb,
                                                      const float* __restrict__ bias,
                                                      short* __restrict__ pT) {
  __shared__ __align__(16) char smem[43008];
  short* ldsB = (short*)smem;               // [3][208*32] bf16 = 39,936 B
  short* bounce = (short*)smem;             // [80][BSTRIDE] 42,240 B (after loop)

  const int tid  = threadIdx.x;
  const int lane = tid & 63;
  const int wid  = tid >> 6;          // 0..14
  const int r16   = lane & 15;
  const int khalf = lane >> 4;        // 0..3
  const int mw = wid % 5;             // M-tile (16 rows)
  const int eh = wid / 5;             // E-third
  const int nbase = (eh == 0) ? 0 : (eh == 1) ? 5 : 9;
  const int ncnt  = (eh == 0) ? 5 : 4;

  const int row0 = blockIdx.x * PBM;

  const int gr = row0 + mw * 16 + r16;
  const float* arow = (gr < NROWS_X) ? (x + (size_t)gr * DD)
                                     : (y + (size_t)(gr - NROWS_X) * DD);
  const float* abase = arow + khalf * 8;

  floatx4 acc[5];
#pragma unroll
  for (int n = 0; n < 5; n++) acc[n] = (floatx4){0.f, 0.f, 0.f, 0.f};

  auto stage = [&](int buf, int ks) {
    if (tid < 832) {                   // 13 waves exactly: wave-uniform
      const int q = tid;
      const int r = q >> 2, c = q & 3;
      glds16(Wb + (size_t)r * DD + ks * 32 + ((c ^ ((r >> 1) & 3)) << 3),
             &ldsB[buf * 6656 + q * 8]);
    }
  };

  floatx4 aCur0, aCur1, aNext0, aNext1;

  stage(0, 0);
  stage(1, 1);
  aCur0 = *(const floatx4*)(abase + 0);
  aCur1 = *(const floatx4*)(abase + 4);

  auto compute = [&](int s) {
    const int buf = s % 3;
    union { short8 s8; uint32_t u[4]; } af;
    af.u[0] = pack2(aCur0.x, aCur0.y);
    af.u[1] = pack2(aCur0.z, aCur0.w);
    af.u[2] = pack2(aCur1.x, aCur1.y);
    af.u[3] = pack2(aCur1.z, aCur1.w);
    const int bcol = (khalf ^ ((r16 >> 1) & 3)) << 3;
#pragma unroll
    for (int n = 0; n < 5; n++) {
      if (n < ncnt) {
        const int erow = (nbase + n) * 16 + r16;
        const short8 bfrag = *(const short8*)&ldsB[buf * 6656 + erow * 32 + bcol];
        acc[n] = __builtin_amdgcn_mfma_f32_16x16x32_bf16(af.s8, bfrag, acc[n], 0, 0, 0);
      }
    }
  };

  for (int s = 0; s < 15; s++) {
    VMCNT_BARRIER(3);                 // B(s) landed on every wave
    if (s + 2 < 16) stage((s + 2) % 3, s + 2);
    aNext0 = *(const floatx4*)(abase + (s + 1) * 32);
    aNext1 = *(const floatx4*)(abase + (s + 1) * 32 + 4);
    compute(s);
    aCur0 = aNext0; aCur1 = aNext1;
  }
  VMCNT_BARRIER(0);
  compute(15);

  __syncthreads();   // all LDS reads done; reuse smem as bounce

  for (int n = 0; n < ncnt; n++) {
    const int e = (nbase + n) * 16 + r16;
    const float bv = (e < EE) ? bias[e] : 0.0f;
#pragma unroll
    for (int rr = 0; rr < 4; rr++) {
      const int lr = mw * 16 + khalf * 4 + rr;
      bounce[lr * BSTRIDE + e] = f2bf(acc[n][rr] + bv);
    }
  }
  __syncthreads();

  for (int c = tid; c < 2080; c += 960) {
    const int n    = c / 160;
    const int rem  = c - n * 160;
    const int lrow = rem >> 1;
    const int ehh  = rem & 1;
    const int g2   = row0 + lrow;
    const short8 piece = *(const short8*)&bounce[lrow * BSTRIDE + n * 16 + ehh * 8];
    *(short8*)&pT[((size_t)((g2 >> 5) * 13 + n)) * 512 + (size_t)(((ehh << 5) | (g2 & 31)) * 8)] = piece;
  }
}

// ---------------- Kernel 2: pair kernel — Bi=2 x Bj=4, grid 512 = 2 blocks/CU
// (4 waves/SIMD: R19 counters showed MfmaUtil 54% at 2 waves/SIMD with LDS-read
// time exposed; doubling TLP at constant per-CU MFMA/LDS work hides it).
// 512 thr = 8 waves = (il = wid>>2, wj = wid&3). A: 2 L-tiles in reg. B: 4 j
// staged as single-j double-buffered groups (26.6 KB each). LDS 61,440 B.
__global__ __launch_bounds__(512, 4) void pair_kernel(const short* __restrict__ xpT,
                                                      const short* __restrict__ ypT,
                                                      float* __restrict__ S) {
  __shared__ __align__(16) char lds[2 * 26624 + 8192];
  float* red = (float*)(lds + 2 * 26624);   // [il 2][j 4][wj 4][64 t] = 8 KB

  const int tid  = threadIdx.x;
  const int lane = tid & 63;
  const int wid  = tid >> 6;       // 0..7
  const int il   = wid >> 2;       // i within pair
  const int wj   = wid & 3;        // lt-pair
  const int bid  = blockIdx.x;
  const int ip   = bid & 31;
  const int jq   = bid >> 5;       // 0..15
  const int i    = ip * 2 + il;
  const int j0   = jq * 4;

  // A global->reg: 2 L-tiles x 13 kk fragments
  short8 a0[NKK], a1[NKK];
  {
    const short* ab0 = xpT + ((size_t)((i * 8 + wj * 2 + 0) * NKK)) * 512 + lane * 8;
    const short* ab1 = xpT + ((size_t)((i * 8 + wj * 2 + 1) * NKK)) * 512 + lane * 8;
#pragma unroll
    for (int kk = 0; kk < NKK; kk++) {
      a0[kk] = *(const short8*)(ab0 + kk * 512);
      a1[kk] = *(const short8*)(ab1 + kk * 512);
    }
  }

  // Stage single j group g (26 chunks = 1664 16B-units) into buf g&1.
  auto stageB = [&](int g) {
    const short* src = ypT + (size_t)(j0 + g) * 26 * 512;
    char* dst = lds + (g & 1) * 26624;
    for (int c = tid; c < 1664; c += 512)
      glds16(src + (size_t)c * 8, dst + c * 16);
  };

  stageB(0);
  __syncthreads();

  for (int g = 0; g < 4; g++) {
    if (g + 1 < 4) stageB(g + 1);

    const short* bbase = (const short*)(lds + (g & 1) * 26624) + lane * 8;

    floatx16 acc00, acc01, acc10, acc11;   // [m][nt]
#pragma unroll
    for (int r = 0; r < 16; r++) {
      acc00[r] = 0.f; acc01[r] = 0.f; acc10[r] = 0.f; acc11[r] = 0.f;
    }

#pragma unroll
    for (int kk = 0; kk < NKK; kk++) {
      const short8 b0 = *(const short8*)(bbase + (0 * NKK + kk) * 512);
      const short8 b1 = *(const short8*)(bbase + (1 * NKK + kk) * 512);
      acc00 = __builtin_amdgcn_mfma_f32_32x32x16_bf16(a0[kk], b0, acc00, 0, 0, 0);
      acc10 = __builtin_amdgcn_mfma_f32_32x32x16_bf16(a1[kk], b0, acc10, 0, 0, 0);
      acc01 = __builtin_amdgcn_mfma_f32_32x32x16_bf16(a0[kk], b1, acc01, 0, 0, 0);
      acc11 = __builtin_amdgcn_mfma_f32_32x32x16_bf16(a1[kk], b1, acc11, 0, 0, 0);
    }

    // Max over this wave's 64 L-rows per column t (C: col = lane&31)
    float v0 = acc00[0], v1 = acc01[0];
#pragma unroll
    for (int r = 0; r < 16; r++) {
      v0 = fmaxf(v0, acc00[r]); v0 = fmaxf(v0, acc10[r]);
      v1 = fmaxf(v1, acc01[r]); v1 = fmaxf(v1, acc11[r]);
    }
    v0 = fmaxf(v0, __shfl_xor(v0, 32, 64));
    v1 = fmaxf(v1, __shfl_xor(v1, 32, 64));
    if (lane < 32) {
      red[((il * 4 + g) * 4 + wj) * 64 + 0 * 32 + lane] = v0;
      red[((il * 4 + g) * 4 + wj) * 64 + 1 * 32 + lane] = v1;
    }

    __syncthreads();   // buf (g+1)&1 staged; red for group g visible
  }

  // Final: 8 (il2,j) combos x 64 t; wave wid takes combo wid.
  {
    const int il2 = wid >> 2;
    const int j   = wid & 3;
    const int t   = lane;
    float v = red[((il2 * 4 + j) * 4 + 0) * 64 + t];
    v = fmaxf(v, red[((il2 * 4 + j) * 4 + 1) * 64 + t]);
    v = fmaxf(v, red[((il2 * 4 + j) * 4 + 2) * 64 + t]);
    v = fmaxf(v, red[((il2 * 4 + j) * 4 + 3) * 64 + t]);
    v += __shfl_xor(v, 1, 64);
    v += __shfl_xor(v, 2, 64);
    v += __shfl_xor(v, 4, 64);
    v += __shfl_xor(v, 8, 64);
    v += __shfl_xor(v, 16, 64);
    v += __shfl_xor(v, 32, 64);
    if (t == 0) S[(ip * 2 + il2) * BB + j0 + j] = v * (1.0f / 64.0f);
  }
}

extern "C" void kernel_launch(void* const* d_in, const int* in_sizes, int n_in,
                              void* d_out, int out_size, void* d_ws, size_t ws_size,
                              hipStream_t stream) {
  const float* x = (const float*)d_in[0];   // 64*256*512
  const float* y = (const float*)d_in[1];   // 64*64*512
  const float* W = (const float*)d_in[2];   // 200*512
  const float* b = (const float*)d_in[3];   // 200
  float* S = (float*)d_out;                 // 64*64

  char* ws = (char*)d_ws;
  short* Wb = (short*)ws;                   // 208*512*2 = 212,992 B
  short* pT = (short*)(ws + 262144);        // 8320 chunks * 1024 B = 8,519,680 B
  short* ypT = pT + (size_t)6656 * 512;     // y starts at chunk 6656

  wcvt_kernel<<<52, 256, 0, stream>>>(W, Wb);
  proj_kernel<<<256, 960, 0, stream>>>(x, y, Wb, b, pT);
  pair_kernel<<<512, 512, 0, stream>>>(pT, ypT, S);
}

// Round 21
// 53.356 us; speedup vs baseline: 1.7183x; 1.5856x over previous
//
#include <hip/hip_runtime.h>
#include <hip/hip_bf16.h>
#include <stdint.h>

// Problem constants
#define BB 64      // batch
#define LL 256     // x seq len
#define TT 64      // y seq len
#define DD 512     // input dim
#define EE 200     // embed dim
#define EP 208     // embed dim padded to 13*16
#define NKK 13     // K-steps in pair kernel (EP/16)
#define NROWS_X 16384   // 64*256
// Fragment-chunk layout: 1 chunk = 32 rows x 16 e = 64 lanes x 16 B = 1024 B.
// lane l holds row (l&31), e_local (l>>5)*8 .. +8, at shorts chunk*512 + l*8.
// Unified pT: chunk index = (global_row >> 5)*13 + n (x rows first, then y).
#define BSTRIDE 264                // proj bounce row stride in shorts
#define PBM 80                     // proj rows per block: 20480/80 = 256 = exact grid

typedef __attribute__((ext_vector_type(8))) short short8;
typedef __attribute__((ext_vector_type(4))) float floatx4;
typedef __attribute__((ext_vector_type(16))) float floatx16;

__device__ __forceinline__ short f2bf(float f) {
  uint32_t u = __builtin_bit_cast(uint32_t, f);
  u = (u + 0x7fffu + ((u >> 16) & 1u)) >> 16;  // RNE
  return (short)u;
}

__device__ __forceinline__ uint32_t pack2(float lo, float hi) {
  return __builtin_amdgcn_perm(__builtin_bit_cast(uint32_t, hi),
                               __builtin_bit_cast(uint32_t, lo), 0x07060302u);
}

typedef const __attribute__((address_space(1))) uint32_t gu32_t;
typedef __attribute__((address_space(3))) uint32_t lu32_t;
__device__ __forceinline__ void glds16(const void* g, void* l) {
  __builtin_amdgcn_global_load_lds((gu32_t*)g, (lu32_t*)l, 16, 0, 0);
}

// counted-vmcnt barrier (FIFO retire; counts glds AND plain vector loads).
#define VMCNT_BARRIER(N) asm volatile("s_waitcnt vmcnt(" #N ") lgkmcnt(0)\n\ts_barrier" ::: "memory")

// ---------------- Kernel 0: W (200x512 f32) -> Wb (208x512 bf16, zero-padded), RNE
__global__ void wcvt_kernel(const float* __restrict__ W, short* __restrict__ Wb) {
  const int t = blockIdx.x * 256 + threadIdx.x;   // 0 .. 13311
  const int base = t * 8;
  const int e = base >> 9;
  short8 o;
  if (e < EE) {
    const floatx4 f0 = *(const floatx4*)(W + base);
    const floatx4 f1 = *(const floatx4*)(W + base + 4);
    o[0] = f2bf(f0.x); o[1] = f2bf(f0.y); o[2] = f2bf(f0.z); o[3] = f2bf(f0.w);
    o[4] = f2bf(f1.x); o[5] = f2bf(f1.y); o[6] = f2bf(f1.z); o[7] = f2bf(f1.w);
  } else {
    o = (short8)0;
  }
  *(short8*)(Wb + base) = o;
}

// ---------------- Kernel 1: projection GEMM -> fragment-layout pT (R19, unchanged)
__global__ __launch_bounds__(960, 1) void proj_kernel(const float* __restrict__ x,
                                                      const float* __restrict__ y,
                                                      const short* __restrict__ Wb,
                                                      const float* __restrict__ bias,
                                                      short* __restrict__ pT) {
  __shared__ __align__(16) char smem[43008];
  short* ldsB = (short*)smem;               // [3][208*32] bf16 = 39,936 B
  short* bounce = (short*)smem;             // [80][BSTRIDE] 42,240 B (after loop)

  const int tid  = threadIdx.x;
  const int lane = tid & 63;
  const int wid  = tid >> 6;          // 0..14
  const int r16   = lane & 15;
  const int khalf = lane >> 4;        // 0..3
  const int mw = wid % 5;             // M-tile (16 rows)
  const int eh = wid / 5;             // E-third
  const int nbase = (eh == 0) ? 0 : (eh == 1) ? 5 : 9;
  const int ncnt  = (eh == 0) ? 5 : 4;

  const int row0 = blockIdx.x * PBM;

  const int gr = row0 + mw * 16 + r16;
  const float* arow = (gr < NROWS_X) ? (x + (size_t)gr * DD)
                                     : (y + (size_t)(gr - NROWS_X) * DD);
  const float* abase = arow + khalf * 8;

  floatx4 acc[5];
#pragma unroll
  for (int n = 0; n < 5; n++) acc[n] = (floatx4){0.f, 0.f, 0.f, 0.f};

  auto stage = [&](int buf, int ks) {
    if (tid < 832) {                   // 13 waves exactly: wave-uniform
      const int q = tid;
      const int r = q >> 2, c = q & 3;
      glds16(Wb + (size_t)r * DD + ks * 32 + ((c ^ ((r >> 1) & 3)) << 3),
             &ldsB[buf * 6656 + q * 8]);
    }
  };

  floatx4 aCur0, aCur1, aNext0, aNext1;

  stage(0, 0);
  stage(1, 1);
  aCur0 = *(const floatx4*)(abase + 0);
  aCur1 = *(const floatx4*)(abase + 4);

  auto compute = [&](int s) {
    const int buf = s % 3;
    union { short8 s8; uint32_t u[4]; } af;
    af.u[0] = pack2(aCur0.x, aCur0.y);
    af.u[1] = pack2(aCur0.z, aCur0.w);
    af.u[2] = pack2(aCur1.x, aCur1.y);
    af.u[3] = pack2(aCur1.z, aCur1.w);
    const int bcol = (khalf ^ ((r16 >> 1) & 3)) << 3;
#pragma unroll
    for (int n = 0; n < 5; n++) {
      if (n < ncnt) {
        const int erow = (nbase + n) * 16 + r16;
        const short8 bfrag = *(const short8*)&ldsB[buf * 6656 + erow * 32 + bcol];
        acc[n] = __builtin_amdgcn_mfma_f32_16x16x32_bf16(af.s8, bfrag, acc[n], 0, 0, 0);
      }
    }
  };

  for (int s = 0; s < 15; s++) {
    VMCNT_BARRIER(3);                 // B(s) landed on every wave
    if (s + 2 < 16) stage((s + 2) % 3, s + 2);
    aNext0 = *(const floatx4*)(abase + (s + 1) * 32);
    aNext1 = *(const floatx4*)(abase + (s + 1) * 32 + 4);
    compute(s);
    aCur0 = aNext0; aCur1 = aNext1;
  }
  VMCNT_BARRIER(0);
  compute(15);

  __syncthreads();   // all LDS reads done; reuse smem as bounce

  for (int n = 0; n < ncnt; n++) {
    const int e = (nbase + n) * 16 + r16;
    const float bv = (e < EE) ? bias[e] : 0.0f;
#pragma unroll
    for (int rr = 0; rr < 4; rr++) {
      const int lr = mw * 16 + khalf * 4 + rr;
      bounce[lr * BSTRIDE + e] = f2bf(acc[n][rr] + bv);
    }
  }
  __syncthreads();

  for (int c = tid; c < 2080; c += 960) {
    const int n    = c / 160;
    const int rem  = c - n * 160;
    const int lrow = rem >> 1;
    const int ehh  = rem & 1;
    const int g2   = row0 + lrow;
    const short8 piece = *(const short8*)&bounce[lrow * BSTRIDE + n * 16 + ehh * 8];
    *(short8*)&pT[((size_t)((g2 >> 5) * 13 + n)) * 512 + (size_t)(((ehh << 5) | (g2 & 31)) * 8)] = piece;
  }
}

// ---------------- Kernel 2: pair kernel — R18 skeleton (grid 256, Bi=2 x Bj=8,
// A-in-reg), B now TRIPLE-buffered single-j groups with 2-ahead prefetch and
// counted VMCNT_BARRIER(3) (replaces R18's full-drain __syncthreads: the old
// sync waited for the just-issued next stage every group). Wave-uniform stage
// counts: waves 0-1 issue 4 glds/stage, waves 2-7 issue 3. LDS 96,256 B.
__global__ __launch_bounds__(512, 1) void pair_kernel(const short* __restrict__ xpT,
                                                      const short* __restrict__ ypT,
                                                      float* __restrict__ S) {
  __shared__ __align__(16) char lds[3 * 26624 + 16384];
  float* red = (float*)(lds + 3 * 26624);   // [il 2][j 8][wj 4][64 t] = 16 KB

  const int tid  = threadIdx.x;
  const int lane = tid & 63;
  const int wid  = tid >> 6;       // 0..7
  const int il   = wid >> 2;       // i within pair
  const int wj   = wid & 3;        // lt-pair
  const int bid  = blockIdx.x;
  const int ip   = bid & 31;
  const int jo   = bid >> 5;       // 0..7
  const int i    = ip * 2 + il;
  const int j0   = jo * 8;

  // A global->reg FIRST (oldest in vmcnt FIFO; retired by first barrier).
  short8 a0[NKK], a1[NKK];
  {
    const short* ab0 = xpT + ((size_t)((i * 8 + wj * 2 + 0) * NKK)) * 512 + lane * 8;
    const short* ab1 = xpT + ((size_t)((i * 8 + wj * 2 + 1) * NKK)) * 512 + lane * 8;
#pragma unroll
    for (int kk = 0; kk < NKK; kk++) {
      a0[kk] = *(const short8*)(ab0 + kk * 512);
      a1[kk] = *(const short8*)(ab1 + kk * 512);
    }
  }

  // Stage single-j group g (1664 16B-units) into buf g%3.
  // Iter counts: waves 0-1 (tid<128) do 4, waves 2-7 do 3 — wave-uniform.
  auto stageB = [&](int g) {
    const short* src = ypT + (size_t)(j0 + g) * 26 * 512;
    char* dst = lds + (g % 3) * 26624;
#pragma unroll
    for (int it = 0; it < 4; it++) {
      const int c = it * 512 + tid;
      if (it < 3 || tid < 128) {
        glds16(src + (size_t)c * 8, dst + c * 16);
      }
    }
  };

  stageB(0);
  stageB(1);

  for (int g = 0; g < 8; g++) {
    // stage g landed: waves 2-7 (3/stage) outstanding <= g(3)+g1(3)=6 -> wait 3
    // drains g; waves 0-1 (4/stage) outstanding <= 8 -> wait 3 drains g + 1 of
    // g+1 (over-strict, correct). Barrier also fences buf reuse: all waves
    // passed barrier g => finished compute g-1, so stageB(g+2) into buf
    // (g+2)%3 == (g-1)%3 is safe.
    VMCNT_BARRIER(3);
    if (g + 2 < 8) stageB(g + 2);

    const short* bbase = (const short*)(lds + (g % 3) * 26624) + lane * 8;

    floatx16 acc00, acc01, acc10, acc11;   // [m][nt]
#pragma unroll
    for (int r = 0; r < 16; r++) {
      acc00[r] = 0.f; acc01[r] = 0.f; acc10[r] = 0.f; acc11[r] = 0.f;
    }

#pragma unroll
    for (int kk = 0; kk < NKK; kk++) {
      const short8 b0 = *(const short8*)(bbase + (0 * NKK + kk) * 512);
      const short8 b1 = *(const short8*)(bbase + (1 * NKK + kk) * 512);
      acc00 = __builtin_amdgcn_mfma_f32_32x32x16_bf16(a0[kk], b0, acc00, 0, 0, 0);
      acc10 = __builtin_amdgcn_mfma_f32_32x32x16_bf16(a1[kk], b0, acc10, 0, 0, 0);
      acc01 = __builtin_amdgcn_mfma_f32_32x32x16_bf16(a0[kk], b1, acc01, 0, 0, 0);
      acc11 = __builtin_amdgcn_mfma_f32_32x32x16_bf16(a1[kk], b1, acc11, 0, 0, 0);
    }

    // Max over this wave's 64 L-rows per column t (C: col = lane&31)
    float v0 = acc00[0], v1 = acc01[0];
#pragma unroll
    for (int r = 0; r < 16; r++) {
      v0 = fmaxf(v0, acc00[r]); v0 = fmaxf(v0, acc10[r]);
      v1 = fmaxf(v1, acc01[r]); v1 = fmaxf(v1, acc11[r]);
    }
    v0 = fmaxf(v0, __shfl_xor(v0, 32, 64));
    v1 = fmaxf(v1, __shfl_xor(v1, 32, 64));
    if (lane < 32) {
      red[((il * 8 + g) * 4 + wj) * 64 + 0 * 32 + lane] = v0;
      red[((il * 8 + g) * 4 + wj) * 64 + 1 * 32 + lane] = v1;
    }
  }

  asm volatile("s_waitcnt vmcnt(0) lgkmcnt(0)" ::: "memory");
  __syncthreads();   // all red writes visible

  // Final: 16 (il2,j) combos x 64 t; wave wid takes combos wid*2, wid*2+1.
#pragma unroll
  for (int rep = 0; rep < 2; rep++) {
    const int combo = wid * 2 + rep;   // 0..15
    const int il2 = combo >> 3;
    const int j   = combo & 7;
    const int t   = lane;
    float v = red[((il2 * 8 + j) * 4 + 0) * 64 + t];
    v = fmaxf(v, red[((il2 * 8 + j) * 4 + 1) * 64 + t]);
    v = fmaxf(v, red[((il2 * 8 + j) * 4 + 2) * 64 + t]);
    v = fmaxf(v, red[((il2 * 8 + j) * 4 + 3) * 64 + t]);
    v += __shfl_xor(v, 1, 64);
    v += __shfl_xor(v, 2, 64);
    v += __shfl_xor(v, 4, 64);
    v += __shfl_xor(v, 8, 64);
    v += __shfl_xor(v, 16, 64);
    v += __shfl_xor(v, 32, 64);
    if (t == 0) S[(ip * 2 + il2) * BB + j0 + j] = v * (1.0f / 64.0f);
  }
}

extern "C" void kernel_launch(void* const* d_in, const int* in_sizes, int n_in,
                              void* d_out, int out_size, void* d_ws, size_t ws_size,
                              hipStream_t stream) {
  const float* x = (const float*)d_in[0];   // 64*256*512
  const float* y = (const float*)d_in[1];   // 64*64*512
  const float* W = (const float*)d_in[2];   // 200*512
  const float* b = (const float*)d_in[3];   // 200
  float* S = (float*)d_out;                 // 64*64

  char* ws = (char*)d_ws;
  short* Wb = (short*)ws;                   // 208*512*2 = 212,992 B
  short* pT = (short*)(ws + 262144);        // 8320 chunks * 1024 B = 8,519,680 B
  short* ypT = pT + (size_t)6656 * 512;     // y starts at chunk 6656

  wcvt_kernel<<<52, 256, 0, stream>>>(W, Wb);
  proj_kernel<<<256, 960, 0, stream>>>(x, y, Wb, b, pT);
  pair_kernel<<<256, 512, 0, stream>>>(pT, ypT, S);
}

// Round 22
// 43.815 us; speedup vs baseline: 2.0925x; 1.2178x over previous
//
#include <hip/hip_runtime.h>
#include <hip/hip_bf16.h>
#include <stdint.h>

// Problem constants
#define BB 64      // batch
#define LL 256     // x seq len
#define TT 64      // y seq len
#define DD 512     // input dim
#define EE 200     // embed dim
#define EP 208     // embed dim padded to 13*16
#define NKK 13     // K-steps in pair kernel (EP/16)
#define NROWS_X 16384   // 64*256
// Fragment-chunk layout: 1 chunk = 32 rows x 16 e = 64 lanes x 16 B = 1024 B.
// lane l holds row (l&31), e_local (l>>5)*8 .. +8, at shorts chunk*512 + l*8.
// Unified pT: chunk index = (global_row >> 5)*13 + n (x rows first, then y).
#define BSTRIDE 264                // proj bounce row stride in shorts
#define PBM 80                     // proj rows per block: 20480/80 = 256 = exact grid

typedef __attribute__((ext_vector_type(8))) short short8;
typedef __attribute__((ext_vector_type(4))) float floatx4;
typedef __attribute__((ext_vector_type(16))) float floatx16;

__device__ __forceinline__ short f2bf(float f) {
  uint32_t u = __builtin_bit_cast(uint32_t, f);
  u = (u + 0x7fffu + ((u >> 16) & 1u)) >> 16;  // RNE
  return (short)u;
}

__device__ __forceinline__ uint32_t pack2(float lo, float hi) {
  return __builtin_amdgcn_perm(__builtin_bit_cast(uint32_t, hi),
                               __builtin_bit_cast(uint32_t, lo), 0x07060302u);
}

typedef const __attribute__((address_space(1))) uint32_t gu32_t;
typedef __attribute__((address_space(3))) uint32_t lu32_t;
__device__ __forceinline__ void glds16(const void* g, void* l) {
  __builtin_amdgcn_global_load_lds((gu32_t*)g, (lu32_t*)l, 16, 0, 0);
}

// counted-vmcnt barrier. Per-wave counts differ (2 or 1 glds/stage); N=1 is
// min-correct for all: every wave has >= its previous stage landed.
#define VMCNT_BARRIER(N) asm volatile("s_waitcnt vmcnt(" #N ") lgkmcnt(0)\n\ts_barrier" ::: "memory")

// ---------------- Kernel 0: W (200x512 f32) -> Wb (208x512 bf16, zero-padded), RNE
__global__ void wcvt_kernel(const float* __restrict__ W, short* __restrict__ Wb) {
  const int t = blockIdx.x * 256 + threadIdx.x;   // 0 .. 13311
  const int base = t * 8;
  const int e = base >> 9;
  short8 o;
  if (e < EE) {
    const floatx4 f0 = *(const floatx4*)(W + base);
    const floatx4 f1 = *(const floatx4*)(W + base + 4);
    o[0] = f2bf(f0.x); o[1] = f2bf(f0.y); o[2] = f2bf(f0.z); o[3] = f2bf(f0.w);
    o[4] = f2bf(f1.x); o[5] = f2bf(f1.y); o[6] = f2bf(f1.z); o[7] = f2bf(f1.w);
  } else {
    o = (short8)0;
  }
  *(short8*)(Wb + base) = o;
}

// ---------------- Kernel 1: projection GEMM -> fragment-layout pT
// R16 structure with EXACT-chunk staging (A 640 + B 832, no dup-writes).
// Wave-uniform splits: tid<640 (wave 10 boundary), tid<512 (wave 8 boundary).
// Counts 2/1 -> vmcnt(1). Bank swizzles: A c^(r&7), B c^((r>>1)&3).
__global__ __launch_bounds__(960, 1) void proj_kernel(const float* __restrict__ x,
                                                      const float* __restrict__ y,
                                                      const short* __restrict__ Wb,
                                                      const float* __restrict__ bias,
                                                      short* __restrict__ pT) {
  __shared__ __align__(16) char smem[70656];
  float* ldsA = (float*)smem;               // [3][80*32] f32  30,720 B
  short* ldsB = (short*)(smem + 30720);     // [3][208*32] bf16 39,936 B
  short* bounce = (short*)smem;             // [80][BSTRIDE] 42,240 B (after loop)

  const int tid  = threadIdx.x;
  const int lane = tid & 63;
  const int wid  = tid >> 6;          // 0..14
  const int r16   = lane & 15;
  const int khalf = lane >> 4;        // 0..3
  const int mw = wid % 5;             // M-tile (16 rows)
  const int eh = wid / 5;             // E-third
  const int nbase = (eh == 0) ? 0 : (eh == 1) ? 5 : 9;
  const int ncnt  = (eh == 0) ? 5 : 4;

  const int row0 = blockIdx.x * PBM;

  floatx4 acc[5];
#pragma unroll
  for (int n = 0; n < 5; n++) acc[n] = (floatx4){0.f, 0.f, 0.f, 0.f};

  // A chunk a (0..639): ldsA[r=a>>3][c=a&7] <- src(r)[ks*32 + (c^(r&7))*4]
  // B chunk q (0..831): ldsB[r=q>>2][c=q&3] <- Wb[r][ks*32 + (c^((r>>1)&3))*8]
  auto stage = [&](int buf, int ks) {
    {
      if (tid < 640) {                 // waves 0-9: A
        const int a = tid;
        const int r = a >> 3, c = a & 7;
        const int gr = row0 + r;
        const float* src = (gr < NROWS_X) ? (x + (size_t)gr * DD)
                                          : (y + (size_t)(gr - NROWS_X) * DD);
        glds16(src + ks * 32 + ((c ^ (r & 7)) << 2),
               &ldsA[buf * 2560 + a * 4]);
      } else {                         // waves 10-14: B[0..319]
        const int q = tid - 640;
        const int r = q >> 2, c = q & 3;
        glds16(Wb + (size_t)r * DD + ks * 32 + ((c ^ ((r >> 1) & 3)) << 3),
               &ldsB[buf * 6656 + q * 8]);
      }
    }
    if (tid < 512) {                   // waves 0-7: B[320..831]
      const int q = tid + 320;
      const int r = q >> 2, c = q & 3;
      glds16(Wb + (size_t)r * DD + ks * 32 + ((c ^ ((r >> 1) & 3)) << 3),
             &ldsB[buf * 6656 + q * 8]);
    }
  };

  auto compute = [&](int s) {
    const int buf = s % 3;
    const int r = mw * 16 + r16;      // 0..79
    const int c0 = (2 * khalf) ^ (r & 7);
    const int c1 = (2 * khalf + 1) ^ (r & 7);
    const floatx4 f0 = *(const floatx4*)&ldsA[buf * 2560 + r * 32 + c0 * 4];
    const floatx4 f1 = *(const floatx4*)&ldsA[buf * 2560 + r * 32 + c1 * 4];
    union { short8 s8; uint32_t u[4]; } af;
    af.u[0] = pack2(f0.x, f0.y);
    af.u[1] = pack2(f0.z, f0.w);
    af.u[2] = pack2(f1.x, f1.y);
    af.u[3] = pack2(f1.z, f1.w);
    const int bcol = (khalf ^ ((r16 >> 1) & 3)) << 3;
#pragma unroll
    for (int n = 0; n < 5; n++) {
      if (n < ncnt) {
        const int erow = (nbase + n) * 16 + r16;
        const short8 bfrag = *(const short8*)&ldsB[buf * 6656 + erow * 32 + bcol];
        acc[n] = __builtin_amdgcn_mfma_f32_16x16x32_bf16(af.s8, bfrag, acc[n], 0, 0, 0);
      }
    }
  };

  stage(0, 0);
  stage(1, 1);

  for (int s = 0; s < 15; s++) {
    VMCNT_BARRIER(1);                 // stage(s) landed on every wave
    if (s + 2 < 16) stage((s + 2) % 3, s + 2);
    compute(s);
  }
  VMCNT_BARRIER(0);
  compute(15);

  __syncthreads();   // all LDS reads done; reuse smem as bounce

  for (int n = 0; n < ncnt; n++) {
    const int e = (nbase + n) * 16 + r16;
    const float bv = (e < EE) ? bias[e] : 0.0f;
#pragma unroll
    for (int rr = 0; rr < 4; rr++) {
      const int lr = mw * 16 + khalf * 4 + rr;
      bounce[lr * BSTRIDE + e] = f2bf(acc[n][rr] + bv);
    }
  }
  __syncthreads();

  for (int c = tid; c < 2080; c += 960) {
    const int n    = c / 160;
    const int rem  = c - n * 160;
    const int lrow = rem >> 1;
    const int ehh  = rem & 1;
    const int gr   = row0 + lrow;
    const short8 piece = *(const short8*)&bounce[lrow * BSTRIDE + n * 16 + ehh * 8];
    *(short8*)&pT[((size_t)((gr >> 5) * 13 + n)) * 512 + (size_t)(((ehh << 5) | (gr & 31)) * 8)] = piece;
  }
}

// ---------------- Kernel 2: pair kernel — Bi=2 x Bj=8 (best measured, R18).
// Grid 256 = 32 ip x 8 jo. 512 thr = 8 waves = (il = wid>>2, wj = wid&3).
// A: each wave loads ITS OWN 2 L-tiles of i=ip*2+il (208 KB/block). B: 8 j
// staged as 4 double-buffered 2-j groups (208 KB/block). __syncthreads per
// group: stage(g+1) issued before ~2.8us compute -> drain residual is small.
__global__ __launch_bounds__(512, 1) void pair_kernel(const short* __restrict__ xpT,
                                                      const short* __restrict__ ypT,
                                                      float* __restrict__ S) {
  __shared__ __align__(16) char lds[2 * 53248 + 16384];
  float* red = (float*)(lds + 2 * 53248);   // [il 2][j 8][wj 4][64 t] = 16 KB

  const int tid  = threadIdx.x;
  const int lane = tid & 63;
  const int wid  = tid >> 6;       // 0..7
  const int il   = wid >> 2;       // i within pair
  const int wj   = wid & 3;        // lt-pair
  const int bid  = blockIdx.x;
  const int ip   = bid & 31;
  const int jo   = bid >> 5;       // 0..7
  const int i    = ip * 2 + il;
  const int j0   = jo * 8;

  // A global->reg: 2 L-tiles x 13 kk fragments (104 VGPR)
  short8 a0[NKK], a1[NKK];
  {
    const short* ab0 = xpT + ((size_t)((i * 8 + wj * 2 + 0) * NKK)) * 512 + lane * 8;
    const short* ab1 = xpT + ((size_t)((i * 8 + wj * 2 + 1) * NKK)) * 512 + lane * 8;
#pragma unroll
    for (int kk = 0; kk < NKK; kk++) {
      a0[kk] = *(const short8*)(ab0 + kk * 512);
      a1[kk] = *(const short8*)(ab1 + kk * 512);
    }
  }

  // Stage 2-j group g (52 chunks = 3328 16B-units) into buf g&1.
  auto stageB = [&](int g) {
    const short* src = ypT + (size_t)(j0 + g * 2) * 26 * 512;
    char* dst = lds + (g & 1) * 53248;
    for (int c = tid; c < 3328; c += 512)
      glds16(src + (size_t)c * 8, dst + c * 16);
  };

  stageB(0);
  __syncthreads();

  for (int g = 0; g < 4; g++) {
    if (g + 1 < 4) stageB(g + 1);

#pragma unroll
    for (int jj2 = 0; jj2 < 2; jj2++) {
      const int j = g * 2 + jj2;     // 0..7 within block
      const short* bbase = (const short*)(lds + (g & 1) * 53248) +
                           (size_t)(jj2 * 26 * 512) + lane * 8;

      floatx16 acc00, acc01, acc10, acc11;   // [m][nt]
#pragma unroll
      for (int r = 0; r < 16; r++) {
        acc00[r] = 0.f; acc01[r] = 0.f; acc10[r] = 0.f; acc11[r] = 0.f;
      }

#pragma unroll
      for (int kk = 0; kk < NKK; kk++) {
        const short8 b0 = *(const short8*)(bbase + (0 * NKK + kk) * 512);
        const short8 b1 = *(const short8*)(bbase + (1 * NKK + kk) * 512);
        acc00 = __builtin_amdgcn_mfma_f32_32x32x16_bf16(a0[kk], b0, acc00, 0, 0, 0);
        acc10 = __builtin_amdgcn_mfma_f32_32x32x16_bf16(a1[kk], b0, acc10, 0, 0, 0);
        acc01 = __builtin_amdgcn_mfma_f32_32x32x16_bf16(a0[kk], b1, acc01, 0, 0, 0);
        acc11 = __builtin_amdgcn_mfma_f32_32x32x16_bf16(a1[kk], b1, acc11, 0, 0, 0);
      }

      // Max over this wave's 64 L-rows per column t (C: col = lane&31)
      float v0 = acc00[0], v1 = acc01[0];
#pragma unroll
      for (int r = 0; r < 16; r++) {
        v0 = fmaxf(v0, acc00[r]); v0 = fmaxf(v0, acc10[r]);
        v1 = fmaxf(v1, acc01[r]); v1 = fmaxf(v1, acc11[r]);
      }
      v0 = fmaxf(v0, __shfl_xor(v0, 32, 64));
      v1 = fmaxf(v1, __shfl_xor(v1, 32, 64));
      if (lane < 32) {
        red[(((il * 8 + j) * 4 + wj)) * 64 + 0 * 32 + lane] = v0;
        red[(((il * 8 + j) * 4 + wj)) * 64 + 1 * 32 + lane] = v1;
      }
    }
    __syncthreads();   // buf (g+1)&1 staged; red for group g visible
  }

  // Final: 16 (il2,j) combos x 64 t; wave wid takes combos wid*2, wid*2+1.
#pragma unroll
  for (int rep = 0; rep < 2; rep++) {
    const int combo = wid * 2 + rep;   // 0..15
    const int il2 = combo >> 3;
    const int j   = combo & 7;
    const int t   = lane;
    float v = red[((il2 * 8 + j) * 4 + 0) * 64 + t];
    v = fmaxf(v, red[((il2 * 8 + j) * 4 + 1) * 64 + t]);
    v = fmaxf(v, red[((il2 * 8 + j) * 4 + 2) * 64 + t]);
    v = fmaxf(v, red[((il2 * 8 + j) * 4 + 3) * 64 + t]);
    v += __shfl_xor(v, 1, 64);
    v += __shfl_xor(v, 2, 64);
    v += __shfl_xor(v, 4, 64);
    v += __shfl_xor(v, 8, 64);
    v += __shfl_xor(v, 16, 64);
    v += __shfl_xor(v, 32, 64);
    if (t == 0) S[(ip * 2 + il2) * BB + j0 + j] = v * (1.0f / 64.0f);
  }
}

extern "C" void kernel_launch(void* const* d_in, const int* in_sizes, int n_in,
                              void* d_out, int out_size, void* d_ws, size_t ws_size,
                              hipStream_t stream) {
  const float* x = (const float*)d_in[0];   // 64*256*512
  const float* y = (const float*)d_in[1];   // 64*64*512
  const float* W = (const float*)d_in[2];   // 200*512
  const float* b = (const float*)d_in[3];   // 200
  float* S = (float*)d_out;                 // 64*64

  char* ws = (char*)d_ws;
  short* Wb = (short*)ws;                   // 208*512*2 = 212,992 B
  short* pT = (short*)(ws + 262144);        // 8320 chunks * 1024 B = 8,519,680 B
  short* ypT = pT + (size_t)6656 * 512;     // y starts at chunk 6656

  wcvt_kernel<<<52, 256, 0, stream>>>(W, Wb);
  proj_kernel<<<256, 960, 0, stream>>>(x, y, Wb, b, pT);
  pair_kernel<<<256, 512, 0, stream>>>(pT, ypT, S);
}